// Round 6
// baseline (169.478 us; speedup 1.0000x reference)
//
#include <hip/hip_runtime.h>
#include <hip/hip_bf16.h>
#include <math.h>

#define BDIM 4096
#define DDIM 2048
#define PDIM 128
#define CDIM 10
#define TB   8192   // 2*B

// exp(cos/TEMP) with TEMP=0.5  ->  exp2(cos * 2/ln2)
#define EXP_SCALE 2.8853900817779268f
#define LAMBDA 0.2f
#define EPS 1e-8f

typedef __bf16 bfv8 __attribute__((ext_vector_type(8)));
typedef float  fv4  __attribute__((ext_vector_type(4)));
typedef unsigned short usv8 __attribute__((ext_vector_type(8)));

__device__ __forceinline__ unsigned short f2bf(float f) {
    unsigned int u = __float_as_uint(f);
    u += 0x7FFFu + ((u >> 16) & 1u);      // round-to-nearest-even
    return (unsigned short)(u >> 16);
}

// ws layout (float index):
//  [0]                    sup_acc
//  [1]                    flag (int)
//  [16 .. 16+8192)        rowsum
//  [16+8192 .. 16+16384)  possum
//  [16400 ..)             phat  [8192][128] bf16   (524288 floats)
//  [540688 ..)            WpT   [128][2048] bf16   (131072 floats)
//  [671760 ..)            WcT   [16][2048]  bf16   (16384 floats)

// ---------------- k0: zero accumulators (+ out) ----------------
__global__ void k0_zero(float* __restrict__ ws_f, float* __restrict__ out) {
    int idx = blockIdx.x * 256 + threadIdx.x;
    if (idx < 16 + 2 * TB) ws_f[idx] = 0.0f;
    if (idx == 0) out[0] = 0.0f;
}

// ---------------- kf: detect int64 label layout ----------------
__global__ void kf_flag(const int* __restrict__ y32, int* __restrict__ flag_out) {
    __shared__ int s_ok;
    if (threadIdx.x == 0) s_ok = 1;
    __syncthreads();
    int ok = 1;
    #pragma unroll
    for (int i = 0; i < 8; ++i) {
        int w = 2 * (threadIdx.x + 256 * i) + 1;   // odd words 1..4095
        if (y32[w] != 0) ok = 0;
    }
    if (!ok) atomicAnd(&s_ok, 0);
    __syncthreads();
    if (threadIdx.x == 0) *flag_out = s_ok;
}

// ---------------- kw: build bf16 transposed weights ----------------
__global__ __launch_bounds__(256) void kw_prep(
    const float* __restrict__ Wp, const float* __restrict__ Wc,
    unsigned short* __restrict__ WpT, unsigned short* __restrict__ WcT)
{
    int idx = blockIdx.x * 256 + threadIdx.x;
    if (idx < PDIM * DDIM) {
        int p = idx >> 11, k = idx & 2047;
        WpT[idx] = f2bf(Wp[(size_t)k * PDIM + p]);
    } else {
        int j = idx - PDIM * DDIM;          // < 16*2048
        int c = j >> 11, k = j & 2047;
        WcT[j] = (c < CDIM) ? f2bf(Wc[(size_t)k * CDIM + c]) : (unsigned short)0;
    }
}

// ---------------- k13: fused proj-GEMM + normalize + digits + CE -----------
// 512 blocks x 512 thr (8 waves). Block owns 16 rows, FULL K=2048.
// Wave w owns proj n-group w (cols w*16..w*16+15); all waves sweep the same
// K range in sync -> x lines shared via L1/L2. Digits: EVERY wave computes
// the full digits MFMA (unconditional, uniform code); 8 identical slabs are
// averaged at the end. A-loads register-double-buffered one chunk ahead.
__global__ __launch_bounds__(512) void k13_fused(
    const float* __restrict__ xi, const float* __restrict__ xj,
    const __bf16* __restrict__ WpT, const __bf16* __restrict__ WcT,
    const int* __restrict__ y, const int* __restrict__ flag_p,
    unsigned short* __restrict__ phat, float* __restrict__ sup_acc)
{
    __shared__ float sproj[16][132];      // 8.25 KB
    __shared__ float sdig[8][16][16];     // 8 KB
    __shared__ float sce[16];

    const int tid = threadIdx.x;
    const int wv = tid >> 6, lane = tid & 63;
    const int l15 = lane & 15, lg = lane >> 4;
    const int R0 = blockIdx.x * 16;
    const float* src = (R0 < BDIM) ? (xi + (size_t)R0 * DDIM)
                                   : (xj + (size_t)(R0 - BDIM) * DDIM);
    const float*  xrow = src + (size_t)l15 * DDIM + lg * 8;
    const __bf16* brow = WpT + (size_t)(wv * 16 + l15) * DDIM + lg * 8;
    const __bf16* crow = WcT + (size_t)l15 * DDIM + lg * 8;

    fv4 acc = {}, accd = {};

    // A double-buffer: chunk = 4 K-slices of 32 (128 K), 16 chunks total
    float4 a0[4], a1[4];
    #pragma unroll
    for (int s = 0; s < 4; ++s) {
        a0[s] = *(const float4*)(xrow + s * 32);
        a1[s] = *(const float4*)(xrow + s * 32 + 4);
    }

    for (int c = 0; c < 16; ++c) {
        // prefetch next A chunk (clamped: c==15 harmlessly re-reads chunk 15)
        const int cn = (c < 15) ? c + 1 : 15;
        float4 na0[4], na1[4];
        #pragma unroll
        for (int s = 0; s < 4; ++s) {
            na0[s] = *(const float4*)(xrow + cn * 128 + s * 32);
            na1[s] = *(const float4*)(xrow + cn * 128 + s * 32 + 4);
        }
        #pragma unroll
        for (int s = 0; s < 4; ++s) {
            bfv8 bb = *(const bfv8*)(brow + c * 128 + s * 32);
            bfv8 bc = *(const bfv8*)(crow + c * 128 + s * 32);
            usv8 au;
            au[0] = f2bf(a0[s].x); au[1] = f2bf(a0[s].y);
            au[2] = f2bf(a0[s].z); au[3] = f2bf(a0[s].w);
            au[4] = f2bf(a1[s].x); au[5] = f2bf(a1[s].y);
            au[6] = f2bf(a1[s].z); au[7] = f2bf(a1[s].w);
            bfv8 a = __builtin_bit_cast(bfv8, au);
            acc  = __builtin_amdgcn_mfma_f32_16x16x32_bf16(a, bb, acc,  0, 0, 0);
            accd = __builtin_amdgcn_mfma_f32_16x16x32_bf16(a, bc, accd, 0, 0, 0);
        }
        #pragma unroll
        for (int s = 0; s < 4; ++s) { a0[s] = na0[s]; a1[s] = na1[s]; }
    }

    // scatter: wave w owns cols w*16+l15; C layout row=lg*4+r, col=l15
    #pragma unroll
    for (int r = 0; r < 4; ++r)
        sproj[lg * 4 + r][wv * 16 + l15] = acc[r];
    #pragma unroll
    for (int r = 0; r < 4; ++r)
        sdig[wv][lg * 4 + r][l15] = accd[r];
    __syncthreads();

    // ---- proj: rsqrt-normalize rows, write bf16 phat ----
    {
        const int row = tid >> 5;            // 0..15, 32 threads per row
        const int cq  = (tid & 31) * 4;
        fv4 p = *(const fv4*)&sproj[row][cq];
        float ssq = p[0]*p[0] + p[1]*p[1] + p[2]*p[2] + p[3]*p[3];
        #pragma unroll
        for (int m = 16; m >= 1; m >>= 1) ssq += __shfl_xor(ssq, m, 32);
        float rn = rsqrtf(ssq);
        ushort4 pk;
        pk.x = f2bf(p[0] * rn); pk.y = f2bf(p[1] * rn);
        pk.z = f2bf(p[2] * rn); pk.w = f2bf(p[3] * rn);
        *(ushort4*)&phat[(size_t)(R0 + row) * PDIM + cq] = pk;
    }

    // ---- digits: average 8 identical slabs, CE via 16-lane shuffles ----
    if (tid < 256) {
        const int drow2 = tid >> 4;          // 0..15
        const int dc    = tid & 15;          // cols 10..15 zero-pad
        float d = 0.0f;
        #pragma unroll
        for (int w = 0; w < 8; ++w) d += sdig[w][drow2][dc];
        d *= 0.125f;
        float dv = (dc < CDIM) ? d : -1e30f;
        float mx = dv;
        #pragma unroll
        for (int m = 8; m >= 1; m >>= 1) mx = fmaxf(mx, __shfl_xor(mx, m, 64));
        float e = (dc < CDIM) ? __expf(d - mx) : 0.0f;
        float s = e;
        #pragma unroll
        for (int m = 8; m >= 1; m >>= 1) s += __shfl_xor(s, m, 64);
        const int rowg = R0 + drow2;
        const int idx  = rowg & (BDIM - 1);
        const int label = (*flag_p) ? y[2 * idx] : y[idx];
        float dl = (dc == label) ? d : 0.0f;
        #pragma unroll
        for (int m = 8; m >= 1; m >>= 1) dl += __shfl_xor(dl, m, 64);
        if (dc == 0) sce[drow2] = (mx + __logf(s)) - dl;
    }
    __syncthreads();
    if (tid == 0) {
        float t = 0.0f;
        #pragma unroll
        for (int r = 0; r < 16; ++r) t += sce[r];
        atomicAdd(sup_acc, t * (1.0f / BDIM));
    }
}

// ---------------- k3: Gram row-sum via bf16 MFMA (upper-triangle tiles) ----
// LDS scatter/gather epilogue; positives need no reduction (one lane each).
__global__ __launch_bounds__(256) void k3_gram_mfma(
    const __bf16* __restrict__ ph,
    float* __restrict__ rowsum, float* __restrict__ possum)
{
    __shared__ float srow[128 * 37 + 4];   // [row][wc*16+l15], stride 37
    __shared__ float scol[128 * 9 + 4];    // [col][wr*4+lg],  stride 9
    __shared__ float spos[128];
    const int tid = threadIdx.x;

    int t = blockIdx.x;
    int ti = 0;
    while (t >= 64 - ti) { t -= 64 - ti; ++ti; }
    const int tj = ti + t;
    const int I0 = ti * 128, J0 = tj * 128;
    const bool diag    = (ti == tj);
    const bool partner = (tj == ti + 32);

    if (tid < 128) spos[tid] = 0.0f;
    __syncthreads();

    const int wid = tid >> 6, lane = tid & 63;
    const int wr = wid >> 1, wc = wid & 1;
    const int l15 = lane & 15, lg = lane >> 4;

    const int arow = I0 + wr * 64 + l15;
    const int brow = J0 + wc * 64 + l15;
    const int kb   = lg * 8;

    fv4 acc[4][4] = {};
    #pragma unroll
    for (int ks = 0; ks < 4; ++ks) {
        bfv8 a[4], b[4];
        #pragma unroll
        for (int m = 0; m < 4; ++m)
            a[m] = *(const bfv8*)(ph + (size_t)(arow + m * 16) * PDIM + ks * 32 + kb);
        #pragma unroll
        for (int n = 0; n < 4; ++n)
            b[n] = *(const bfv8*)(ph + (size_t)(brow + n * 16) * PDIM + ks * 32 + kb);
        #pragma unroll
        for (int m = 0; m < 4; ++m)
            #pragma unroll
            for (int n = 0; n < 4; ++n)
                acc[m][n] = __builtin_amdgcn_mfma_f32_16x16x32_bf16(a[m], b[n], acc[m][n], 0, 0, 0);
    }

    // epilogue: exp, diag-mask, per-lane row/col partials
    float rs_l[4][4];
    float cs_l[4] = {0, 0, 0, 0};
    #pragma unroll
    for (int m = 0; m < 4; ++m)
        #pragma unroll
        for (int r = 0; r < 4; ++r) rs_l[m][r] = 0.0f;

    #pragma unroll
    for (int m = 0; m < 4; ++m) {
        const int ribase = wr * 64 + m * 16 + lg * 4;
        #pragma unroll
        for (int n = 0; n < 4; ++n) {
            const int cj = wc * 64 + n * 16 + l15;
            #pragma unroll
            for (int r = 0; r < 4; ++r) {
                const int ri = ribase + r;
                float e = exp2f(acc[m][n][r] * EXP_SCALE);
                if (diag && ri == cj) e = 0.0f;
                rs_l[m][r] += e;
                cs_l[n] += e;
                if (partner && ri == cj) atomicAdd(&spos[ri], e);
            }
        }
    }

    // scatter partials (each slot written by exactly one lane)
    #pragma unroll
    for (int m = 0; m < 4; ++m)
        #pragma unroll
        for (int r = 0; r < 4; ++r)
            srow[(wr * 64 + m * 16 + lg * 4 + r) * 37 + wc * 16 + l15] = rs_l[m][r];
    #pragma unroll
    for (int n = 0; n < 4; ++n)
        scol[(wc * 64 + n * 16 + l15) * 9 + wr * 4 + lg] = cs_l[n];
    __syncthreads();

    // gather + one global atomic per row/col
    if (tid < 128) {
        float s = 0.0f;
        #pragma unroll
        for (int q = 0; q < 32; ++q) s += srow[tid * 37 + q];
        atomicAdd(&rowsum[I0 + tid], s);
        if (partner) atomicAdd(&possum[I0 + tid], spos[tid]);
    } else if (!diag) {
        const int col = tid - 128;
        float s = 0.0f;
        #pragma unroll
        for (int q = 0; q < 8; ++q) s += scol[col * 9 + q];
        atomicAdd(&rowsum[J0 + col], s);
        if (partner) atomicAdd(&possum[J0 + col], spos[col]);
    }
}

// ---------------- k4: final reduction (16 blocks) ----------------
__global__ __launch_bounds__(256) void k4_final(
    const float* __restrict__ rowsum, const float* __restrict__ possum,
    const float* __restrict__ sup_acc, float* __restrict__ out)
{
    __shared__ float red[4];
    const int tid = threadIdx.x;
    const int gid = blockIdx.x * 256 + tid;
    float s = 0.0f;
    #pragma unroll
    for (int i = 0; i < 2; ++i) {
        int r = gid * 2 + i;
        s += -__logf(possum[r] / rowsum[r] + EPS);
    }
    #pragma unroll
    for (int m = 32; m >= 1; m >>= 1) s += __shfl_xor(s, m, 64);
    if ((tid & 63) == 0) red[tid >> 6] = s;
    __syncthreads();
    if (tid == 0) {
        float part = (red[0] + red[1] + red[2] + red[3]) * (1.0f / TB);
        if (blockIdx.x == 0) part += LAMBDA * sup_acc[0];
        atomicAdd(out, part);
    }
}

extern "C" void kernel_launch(void* const* d_in, const int* in_sizes, int n_in,
                              void* d_out, int out_size, void* d_ws, size_t ws_size,
                              hipStream_t stream) {
    const float* xi = (const float*)d_in[1];
    const float* xj = (const float*)d_in[2];
    const int*   y  = (const int*)d_in[3];
    const float* Wp = (const float*)d_in[4];
    const float* Wc = (const float*)d_in[5];
    float* out  = (float*)d_out;

    float* ws_f   = (float*)d_ws;
    float* sup    = ws_f;
    int*   flag   = (int*)(ws_f + 1);
    float* rowsum = ws_f + 16;
    float* possum = ws_f + 16 + TB;
    unsigned short* phat_u = (unsigned short*)(ws_f + 16 + 2 * TB);
    unsigned short* WpT_u  = (unsigned short*)(ws_f + 540688);
    unsigned short* WcT_u  = (unsigned short*)(ws_f + 671760);

    k0_zero<<<(16 + 2 * TB + 255) / 256, 256, 0, stream>>>(ws_f, out);
    kf_flag<<<1, 256, 0, stream>>>(y, flag);
    kw_prep<<<(PDIM * DDIM + 16 * DDIM) / 256, 256, 0, stream>>>(Wp, Wc, WpT_u, WcT_u);
    k13_fused<<<512, 512, 0, stream>>>(xi, xj, (const __bf16*)WpT_u, (const __bf16*)WcT_u,
                                       y, flag, phat_u, sup);
    k3_gram_mfma<<<2080, 256, 0, stream>>>((const __bf16*)phat_u, rowsum, possum);
    k4_final<<<16, 256, 0, stream>>>(rowsum, possum, sup, out);
}

// Round 8
// 96.522 us; speedup vs baseline: 1.7558x; 1.7558x over previous
//
#include <hip/hip_runtime.h>
#include <hip/hip_bf16.h>
#include <math.h>

#define BDIM 4096
#define DDIM 2048
#define PDIM 128
#define CDIM 10
#define TB   8192   // 2*B

// exp(cos/TEMP) with TEMP=0.5  ->  exp2(cos * 2/ln2)
#define EXP_SCALE 2.8853900817779268f
#define LAMBDA 0.2f
#define EPS 1e-8f

typedef __bf16 bfv8 __attribute__((ext_vector_type(8)));
typedef float  fv4  __attribute__((ext_vector_type(4)));
typedef unsigned short usv8 __attribute__((ext_vector_type(8)));

__device__ __forceinline__ unsigned short f2bf(float f) {
    unsigned int u = __float_as_uint(f);
    u += 0x7FFFu + ((u >> 16) & 1u);      // round-to-nearest-even
    return (unsigned short)(u >> 16);
}

// ws layout (float index):
//  [0]                    sup_acc
//  [1]                    flag (int)
//  [16 .. 16+8192)        rowsum
//  [16+8192 .. 16+16384)  possum
//  [16400 ..)             phat  [8192][128] bf16   (524288 floats)
//  [540688 ..)            WpT   [128][2048] bf16   (131072 floats)
//  [671760 ..)            WcT   [16][2048]  bf16   (16384 floats)

// ---------------- k0: zero accumulators (+ out) ----------------
__global__ void k0_zero(float* __restrict__ ws_f, float* __restrict__ out) {
    int idx = blockIdx.x * 256 + threadIdx.x;
    if (idx < 16 + 2 * TB) ws_f[idx] = 0.0f;
    if (idx == 0) out[0] = 0.0f;
}

// ---------------- kf: detect int64 label layout ----------------
__global__ void kf_flag(const int* __restrict__ y32, int* __restrict__ flag_out) {
    __shared__ int s_ok;
    if (threadIdx.x == 0) s_ok = 1;
    __syncthreads();
    int ok = 1;
    #pragma unroll
    for (int i = 0; i < 8; ++i) {
        int w = 2 * (threadIdx.x + 256 * i) + 1;   // odd words 1..4095
        if (y32[w] != 0) ok = 0;
    }
    if (!ok) atomicAnd(&s_ok, 0);
    __syncthreads();
    if (threadIdx.x == 0) *flag_out = s_ok;
}

// ---------------- kw: build bf16 transposed weights ----------------
__global__ __launch_bounds__(256) void kw_prep(
    const float* __restrict__ Wp, const float* __restrict__ Wc,
    unsigned short* __restrict__ WpT, unsigned short* __restrict__ WcT)
{
    int idx = blockIdx.x * 256 + threadIdx.x;
    if (idx < PDIM * DDIM) {
        int p = idx >> 11, k = idx & 2047;
        WpT[idx] = f2bf(Wp[(size_t)k * PDIM + p]);
    } else {
        int j = idx - PDIM * DDIM;          // < 16*2048
        int c = j >> 11, k = j & 2047;
        WcT[j] = (c < CDIM) ? f2bf(Wc[(size_t)k * CDIM + c]) : (unsigned short)0;
    }
}

// ---------------- k13: fused proj-GEMM + normalize + digits + CE -----------
// 512 blocks x 512 thr (8 waves). Block owns 16 rows, K staged in LDS tiles
// of BK=128 (double-buffered bf16, XOR-swizzled). Staging loads are fully
// coalesced; fp32->bf16 once. Wave w owns proj n-tile w; digits rotate
// per-tile ((kt&7)==wv). One barrier per tile.
// SWIZZLE (both sides, same involution): byte-col c of row r lives at
// (c ^ ((r&7)<<4)). Read offset computed as (full_col ^ swz) — XOR applied
// to the COMPLETE column offset (R7 bug: XOR before +ks*64 carried into
// the row bits and crossed buffers).
__global__ __launch_bounds__(512) void k13_fused(
    const float* __restrict__ xi, const float* __restrict__ xj,
    const __bf16* __restrict__ WpT, const __bf16* __restrict__ WcT,
    const int* __restrict__ y, const int* __restrict__ flag_p,
    unsigned short* __restrict__ phat, float* __restrict__ sup_acc)
{
    __shared__ unsigned short Xs[2][16 * 128];  // 8 KB bf16, swizzled
    __shared__ float sproj[16][132];            // 8.25 KB
    __shared__ float sdig[8][16][16];           // 8 KB
    __shared__ float sce[16];

    const int tid = threadIdx.x;
    const int wv = tid >> 6, lane = tid & 63;
    const int l15 = lane & 15, lg = lane >> 4;
    const int R0 = blockIdx.x * 16;
    const float* src = (R0 < BDIM) ? (xi + (size_t)R0 * DDIM)
                                   : (xj + (size_t)(R0 - BDIM) * DDIM);
    // coalesced staging map: row = tid>>5, float-col = (tid&31)*4
    const float* gsrc = src + (size_t)(tid >> 5) * DDIM + (tid & 31) * 4;
    const int wbyte = (tid >> 5) * 256 + (((tid & 31) * 8) ^ (((tid >> 5) & 7) << 4));
    // A-fragment read: row l15; column byte offset (lg*16 + ks*64) ^ swz
    const int arowb = l15 * 256;
    const int swz   = (l15 & 7) << 4;

    const __bf16* brow = WpT + (size_t)(wv * 16 + l15) * DDIM + lg * 8;
    const __bf16* crow = WcT + (size_t)l15 * DDIM + lg * 8;

    fv4 acc = {}, accd = {};

    // stage tile 0
    {
        float4 f = *(const float4*)gsrc;
        ushort4 w;
        w.x = f2bf(f.x); w.y = f2bf(f.y); w.z = f2bf(f.z); w.w = f2bf(f.w);
        *(ushort4*)((char*)&Xs[0][0] + wbyte) = w;
    }

    for (int kt = 0; kt < 16; ++kt) {
        __syncthreads();
        // issue next-tile load AFTER the barrier: stays in flight over compute
        float4 f4n = make_float4(0.f, 0.f, 0.f, 0.f);
        if (kt < 15) f4n = *(const float4*)(gsrc + (size_t)(kt + 1) * 128);

        const char* xb = (const char*)&Xs[kt & 1][0];
        #pragma unroll
        for (int ks = 0; ks < 4; ++ks) {
            bfv8 a = *(const bfv8*)(xb + arowb + ((lg * 16 + ks * 64) ^ swz));
            bfv8 b = *(const bfv8*)(brow + (size_t)kt * 128 + ks * 32);
            acc = __builtin_amdgcn_mfma_f32_16x16x32_bf16(a, b, acc, 0, 0, 0);
        }
        if ((kt & 7) == wv) {    // wave-uniform rotation: 2 tiles per wave
            #pragma unroll
            for (int ks = 0; ks < 4; ++ks) {
                bfv8 a = *(const bfv8*)(xb + arowb + ((lg * 16 + ks * 64) ^ swz));
                bfv8 bc = *(const bfv8*)(crow + (size_t)kt * 128 + ks * 32);
                accd = __builtin_amdgcn_mfma_f32_16x16x32_bf16(a, bc, accd, 0, 0, 0);
            }
        }
        if (kt < 15) {
            ushort4 w;
            w.x = f2bf(f4n.x); w.y = f2bf(f4n.y); w.z = f2bf(f4n.z); w.w = f2bf(f4n.w);
            *(ushort4*)((char*)&Xs[(kt + 1) & 1][0] + wbyte) = w;
        }
    }

    // scatter: wave w owns cols w*16+l15; C layout row=lg*4+r, col=l15
    #pragma unroll
    for (int r = 0; r < 4; ++r)
        sproj[lg * 4 + r][wv * 16 + l15] = acc[r];
    #pragma unroll
    for (int r = 0; r < 4; ++r)
        sdig[wv][lg * 4 + r][l15] = accd[r];
    __syncthreads();

    // ---- proj: rsqrt-normalize rows, write bf16 phat ----
    {
        const int row = tid >> 5;            // 0..15, 32 threads per row
        const int cq  = (tid & 31) * 4;
        fv4 p = *(const fv4*)&sproj[row][cq];
        float ssq = p[0]*p[0] + p[1]*p[1] + p[2]*p[2] + p[3]*p[3];
        #pragma unroll
        for (int m = 16; m >= 1; m >>= 1) ssq += __shfl_xor(ssq, m, 32);
        float rn = rsqrtf(ssq);
        ushort4 pk;
        pk.x = f2bf(p[0] * rn); pk.y = f2bf(p[1] * rn);
        pk.z = f2bf(p[2] * rn); pk.w = f2bf(p[3] * rn);
        *(ushort4*)&phat[(size_t)(R0 + row) * PDIM + cq] = pk;
    }

    // ---- digits: sum 8 partial K-slabs, CE via 16-lane shuffles ----
    if (tid < 256) {
        const int drow2 = tid >> 4;          // 0..15
        const int dc    = tid & 15;          // cols 10..15 zero-pad
        float d = 0.0f;
        #pragma unroll
        for (int w = 0; w < 8; ++w) d += sdig[w][drow2][dc];
        float dv = (dc < CDIM) ? d : -1e30f;
        float mx = dv;
        #pragma unroll
        for (int m = 8; m >= 1; m >>= 1) mx = fmaxf(mx, __shfl_xor(mx, m, 64));
        float e = (dc < CDIM) ? __expf(d - mx) : 0.0f;
        float s = e;
        #pragma unroll
        for (int m = 8; m >= 1; m >>= 1) s += __shfl_xor(s, m, 64);
        const int rowg = R0 + drow2;
        const int idx  = rowg & (BDIM - 1);
        const int label = (*flag_p) ? y[2 * idx] : y[idx];
        float dl = (dc == label) ? d : 0.0f;
        #pragma unroll
        for (int m = 8; m >= 1; m >>= 1) dl += __shfl_xor(dl, m, 64);
        if (dc == 0) sce[drow2] = (mx + __logf(s)) - dl;
    }
    __syncthreads();
    if (tid == 0) {
        float t = 0.0f;
        #pragma unroll
        for (int r = 0; r < 16; ++r) t += sce[r];
        atomicAdd(sup_acc, t * (1.0f / BDIM));
    }
}

// ---------------- k3: Gram row-sum via bf16 MFMA (upper-triangle tiles) ----
// LDS scatter/gather epilogue; positives need no reduction (one lane each).
__global__ __launch_bounds__(256) void k3_gram_mfma(
    const __bf16* __restrict__ ph,
    float* __restrict__ rowsum, float* __restrict__ possum)
{
    __shared__ float srow[128 * 37 + 4];   // [row][wc*16+l15], stride 37
    __shared__ float scol[128 * 9 + 4];    // [col][wr*4+lg],  stride 9
    __shared__ float spos[128];
    const int tid = threadIdx.x;

    int t = blockIdx.x;
    int ti = 0;
    while (t >= 64 - ti) { t -= 64 - ti; ++ti; }
    const int tj = ti + t;
    const int I0 = ti * 128, J0 = tj * 128;
    const bool diag    = (ti == tj);
    const bool partner = (tj == ti + 32);

    if (tid < 128) spos[tid] = 0.0f;
    __syncthreads();

    const int wid = tid >> 6, lane = tid & 63;
    const int wr = wid >> 1, wc = wid & 1;
    const int l15 = lane & 15, lg = lane >> 4;

    const int arow = I0 + wr * 64 + l15;
    const int brow = J0 + wc * 64 + l15;
    const int kb   = lg * 8;

    fv4 acc[4][4] = {};
    #pragma unroll
    for (int ks = 0; ks < 4; ++ks) {
        bfv8 a[4], b[4];
        #pragma unroll
        for (int m = 0; m < 4; ++m)
            a[m] = *(const bfv8*)(ph + (size_t)(arow + m * 16) * PDIM + ks * 32 + kb);
        #pragma unroll
        for (int n = 0; n < 4; ++n)
            b[n] = *(const bfv8*)(ph + (size_t)(brow + n * 16) * PDIM + ks * 32 + kb);
        #pragma unroll
        for (int m = 0; m < 4; ++m)
            #pragma unroll
            for (int n = 0; n < 4; ++n)
                acc[m][n] = __builtin_amdgcn_mfma_f32_16x16x32_bf16(a[m], b[n], acc[m][n], 0, 0, 0);
    }

    // epilogue: exp, diag-mask, per-lane row/col partials
    float rs_l[4][4];
    float cs_l[4] = {0, 0, 0, 0};
    #pragma unroll
    for (int m = 0; m < 4; ++m)
        #pragma unroll
        for (int r = 0; r < 4; ++r) rs_l[m][r] = 0.0f;

    #pragma unroll
    for (int m = 0; m < 4; ++m) {
        const int ribase = wr * 64 + m * 16 + lg * 4;
        #pragma unroll
        for (int n = 0; n < 4; ++n) {
            const int cj = wc * 64 + n * 16 + l15;
            #pragma unroll
            for (int r = 0; r < 4; ++r) {
                const int ri = ribase + r;
                float e = exp2f(acc[m][n][r] * EXP_SCALE);
                if (diag && ri == cj) e = 0.0f;
                rs_l[m][r] += e;
                cs_l[n] += e;
                if (partner && ri == cj) atomicAdd(&spos[ri], e);
            }
        }
    }

    // scatter partials (each slot written by exactly one lane)
    #pragma unroll
    for (int m = 0; m < 4; ++m)
        #pragma unroll
        for (int r = 0; r < 4; ++r)
            srow[(wr * 64 + m * 16 + lg * 4 + r) * 37 + wc * 16 + l15] = rs_l[m][r];
    #pragma unroll
    for (int n = 0; n < 4; ++n)
        scol[(wc * 64 + n * 16 + l15) * 9 + wr * 4 + lg] = cs_l[n];
    __syncthreads();

    // gather + one global atomic per row/col
    if (tid < 128) {
        float s = 0.0f;
        #pragma unroll
        for (int q = 0; q < 32; ++q) s += srow[tid * 37 + q];
        atomicAdd(&rowsum[I0 + tid], s);
        if (partner) atomicAdd(&possum[I0 + tid], spos[tid]);
    } else if (!diag) {
        const int col = tid - 128;
        float s = 0.0f;
        #pragma unroll
        for (int q = 0; q < 8; ++q) s += scol[col * 9 + q];
        atomicAdd(&rowsum[J0 + col], s);
        if (partner) atomicAdd(&possum[J0 + col], spos[col]);
    }
}

// ---------------- k4: final reduction (16 blocks) ----------------
__global__ __launch_bounds__(256) void k4_final(
    const float* __restrict__ rowsum, const float* __restrict__ possum,
    const float* __restrict__ sup_acc, float* __restrict__ out)
{
    __shared__ float red[4];
    const int tid = threadIdx.x;
    const int gid = blockIdx.x * 256 + tid;
    float s = 0.0f;
    #pragma unroll
    for (int i = 0; i < 2; ++i) {
        int r = gid * 2 + i;
        s += -__logf(possum[r] / rowsum[r] + EPS);
    }
    #pragma unroll
    for (int m = 32; m >= 1; m >>= 1) s += __shfl_xor(s, m, 64);
    if ((tid & 63) == 0) red[tid >> 6] = s;
    __syncthreads();
    if (tid == 0) {
        float part = (red[0] + red[1] + red[2] + red[3]) * (1.0f / TB);
        if (blockIdx.x == 0) part += LAMBDA * sup_acc[0];
        atomicAdd(out, part);
    }
}

extern "C" void kernel_launch(void* const* d_in, const int* in_sizes, int n_in,
                              void* d_out, int out_size, void* d_ws, size_t ws_size,
                              hipStream_t stream) {
    const float* xi = (const float*)d_in[1];
    const float* xj = (const float*)d_in[2];
    const int*   y  = (const int*)d_in[3];
    const float* Wp = (const float*)d_in[4];
    const float* Wc = (const float*)d_in[5];
    float* out  = (float*)d_out;

    float* ws_f   = (float*)d_ws;
    float* sup    = ws_f;
    int*   flag   = (int*)(ws_f + 1);
    float* rowsum = ws_f + 16;
    float* possum = ws_f + 16 + TB;
    unsigned short* phat_u = (unsigned short*)(ws_f + 16 + 2 * TB);
    unsigned short* WpT_u  = (unsigned short*)(ws_f + 540688);
    unsigned short* WcT_u  = (unsigned short*)(ws_f + 671760);

    k0_zero<<<(16 + 2 * TB + 255) / 256, 256, 0, stream>>>(ws_f, out);
    kf_flag<<<1, 256, 0, stream>>>(y, flag);
    kw_prep<<<(PDIM * DDIM + 16 * DDIM) / 256, 256, 0, stream>>>(Wp, Wc, WpT_u, WcT_u);
    k13_fused<<<512, 512, 0, stream>>>(xi, xj, (const __bf16*)WpT_u, (const __bf16*)WcT_u,
                                       y, flag, phat_u, sup);
    k3_gram_mfma<<<2080, 256, 0, stream>>>((const __bf16*)phat_u, rowsum, possum);
    k4_final<<<16, 256, 0, stream>>>(rowsum, possum, sup, out);
}